// Round 2
// baseline (1562.095 us; speedup 1.0000x reference)
//
#include <hip/hip_runtime.h>

// ---------------------------------------------------------------------------
// Bidirectional GRU (B=128, T=512, E=H=256) + linear head.
// Phase 1 (R14): gate table with per-thread-contiguous layout: the 24 bf16
//   gate values one rnn thread needs per step live in one 48 B chunk:
//   chunk = ((d*8+w)*4+q)*24, slots: xr:8l, xz:8l+4, xn:16+4l, +r.
//   (R13 bug: stride was 48 ELEMENTS instead of 24 -> rows overlapped.)
// Phase 2 (R14): xg gathered as 3x global_load_dwordx4 straight into
//   registers, prefetched one step ahead; main-loop barrier is raw
//   s_barrier + lgkmcnt(0) only, so gathers fly across it (no vmcnt(0)
//   drain). xr/xz fold into the MFMA accumulator init. Gate-major MFMA
//   schedule (pass A = r+z, pass B = n) kept from R12.
// ---------------------------------------------------------------------------

typedef float f32x4 __attribute__((ext_vector_type(4)));
typedef short s16x8 __attribute__((ext_vector_type(8)));

#define VOCAB   30000
#define GCOLS   1536
#define HB_STR  280     // bf16 elems per h/emb row (560 B)
#define HBUF    (16 * HB_STR)
#define HS_STR  260     // f32 elems per h row for epilogue
#define SRF     (-1.4426950408889634f)   // -log2(e), sigmoid gates
#define SNF     (2.8853900817779268f)    // 2*log2(e), tanh gate

#if defined(__has_builtin)
#if __has_builtin(__builtin_amdgcn_cvt_pk_bf16_f32)
#define HAVE_PK 1
#endif
#endif

static __device__ __forceinline__ unsigned short f2bf(float f) {
    unsigned u = __builtin_bit_cast(unsigned, f);
    u += 0x7fffu + ((u >> 16) & 1u);            // RNE
    return (unsigned short)(u >> 16);
}
#ifdef HAVE_PK
typedef __bf16 bf16x2_t __attribute__((ext_vector_type(2)));
static __device__ __forceinline__ unsigned pk2(float a, float b) {
    bf16x2_t v = __builtin_amdgcn_cvt_pk_bf16_f32(a, b);
    return __builtin_bit_cast(unsigned, v);
}
#else
static __device__ __forceinline__ unsigned pk2(float a, float b) {
    return (unsigned)f2bf(a) | ((unsigned)f2bf(b) << 16);
}
#endif
static __device__ __forceinline__ float bf_lo(unsigned v) {
    return __builtin_bit_cast(float, v << 16);
}
static __device__ __forceinline__ float bf_hi(unsigned v) {
    return __builtin_bit_cast(float, v & 0xffff0000u);
}
static __device__ __forceinline__ s16x8 pack_bf8(float4 a, float4 b, float s) {
    union { s16x8 v; unsigned u[4]; } r;
    r.u[0] = pk2(a.x * s, a.y * s); r.u[1] = pk2(a.z * s, a.w * s);
    r.u[2] = pk2(b.x * s, b.y * s); r.u[3] = pk2(b.z * s, b.w * s);
    return r.v;
}
static __device__ __forceinline__ f32x4 mfma16(s16x8 a, s16x8 b, f32x4 c) {
    return __builtin_amdgcn_mfma_f32_16x16x32_bf16(a, b, c, 0, 0, 0);
}
static __device__ __forceinline__ float sig2(float x) {      // 1/(1+2^x)
    return __builtin_amdgcn_rcpf(1.0f + __builtin_amdgcn_exp2f(x));
}
// Raw barrier that drains ONLY lgkmcnt (h-exchange LDS traffic); global
// gather loads issued earlier in the step stay in flight across it.
static __device__ __forceinline__ void lgkm_barrier() {
    __builtin_amdgcn_sched_barrier(0);
    asm volatile("s_waitcnt lgkmcnt(0)" ::: "memory");
    __builtin_amdgcn_sched_barrier(0);
    __builtin_amdgcn_s_barrier();
    __builtin_amdgcn_sched_barrier(0);
}

// ---------------------------------------------------------------------------
// Phase 1: gate table.  grid (2 dirs, 128 M-slices), 512 threads.
// G layout (per token row of 1536 bf16):
//   chunk = ((d*8 + w)*4 + (u>>2))*24,  in-chunk = slot + (u&3)
//   slot: r-gate half l -> 8*l ; z-gate -> 8*l+4 ; n-gate -> 16 + 4*l
// so consumer thread (d,w,q) reads [xr0 xz0][xr1 xz1][xn0 xn1] = 3 dwordx4.
// ---------------------------------------------------------------------------
__global__ __launch_bounds__(512, 2)
void gru_table_kernel(const float* __restrict__ emb,
                      const float* __restrict__ Wih_f, const float* __restrict__ bih_f,
                      const float* __restrict__ bhh_f,
                      const float* __restrict__ Wih_b, const float* __restrict__ bih_b,
                      const float* __restrict__ bhh_b,
                      unsigned short* __restrict__ G) {
    __shared__ unsigned short aS[2][16 * HB_STR];    // dbuf emb tile (bf16)

    const int tid  = threadIdx.x;
    const int lane = tid & 63;
    const int w    = tid >> 6;       // wave 0..7
    const int u    = lane & 15;
    const int q    = lane >> 4;
    const int d    = blockIdx.x;     // 0 fwd, 1 bwd
    const int by   = blockIdx.y;     // 0..127

    const float* Wih = d ? Wih_b : Wih_f;
    const float* bih = d ? bih_b : bih_f;
    const float* bhh = d ? bhh_b : bhh_f;

    s16x8 breg[48];
    float beta[6];
#pragma unroll
    for (int t = 0; t < 6; ++t) {
        const int orig = (t >> 1) * 256 + 32 * w + ((t & 1) << 4) + u;
        const float scl = (t < 4) ? SRF : SNF;
        beta[t] = (bih[orig] + ((t < 4) ? bhh[orig] : 0.0f)) * scl;
#pragma unroll
        for (int kt = 0; kt < 8; ++kt) {
            const float* p = Wih + orig * 256 + kt * 32 + q * 8;
            breg[t * 8 + kt] =
                pack_bf8(*(const float4*)p, *(const float4*)(p + 4), scl);
        }
    }

    const int srow = tid >> 5;
    const int sc8  = (tid & 31) * 8;

    {
        const float* p = emb + (size_t)(by * 16 + srow) * 256 + sc8;
        float4 e0 = *(const float4*)p, e1 = *(const float4*)(p + 4);
        unsigned* dp = (unsigned*)&aS[0][srow * HB_STR + sc8];
        dp[0] = pk2(e0.x, e0.y); dp[1] = pk2(e0.z, e0.w);
        dp[2] = pk2(e1.x, e1.y); dp[3] = pk2(e1.z, e1.w);
    }
    __syncthreads();

    const int ubase = ((d * 8 + w) * 4 + (u >> 2)) * 24 + (u & 3);

    for (int i = 0;; ++i) {
        const int mt = by + i * 128;
        if (mt >= 1875) break;
        const int mtn = mt + 128;
        const bool has_next = (mtn < 1875);
        const int buf = i & 1;

        float4 e0, e1;
        if (has_next) {
            const float* p = emb + (size_t)(mtn * 16 + srow) * 256 + sc8;
            e0 = *(const float4*)p;
            e1 = *(const float4*)(p + 4);
        }

        const int v0 = mt * 16;
#pragma unroll
        for (int l = 0; l < 2; ++l) {
            f32x4 a0 = {0.f, 0.f, 0.f, 0.f}, a1 = a0, a2 = a0;
#pragma unroll
            for (int kt = 0; kt < 8; ++kt) {
                s16x8 af = *(const s16x8*)&aS[buf][u * HB_STR + kt * 32 + q * 8];
                a0 = mfma16(af, breg[(0 + l) * 8 + kt], a0);
                a1 = mfma16(af, breg[(2 + l) * 8 + kt], a1);
                a2 = mfma16(af, breg[(4 + l) * 8 + kt], a2);
            }
#pragma unroll
            for (int g = 0; g < 3; ++g) {
                const f32x4 a = (g == 0) ? a0 : (g == 1) ? a1 : a2;
                const int t    = 2 * g + l;
                const int slot = (g < 2) ? (8 * l + 4 * g) : (16 + 4 * l);
                unsigned short* gp =
                    G + (size_t)(v0 + q * 4) * GCOLS + ubase + slot;
#pragma unroll
                for (int r = 0; r < 4; ++r)
                    gp[(size_t)r * GCOLS] = f2bf(a[r] + beta[t]);
            }
        }
        if (has_next) {
            unsigned* dp = (unsigned*)&aS[buf ^ 1][srow * HB_STR + sc8];
            dp[0] = pk2(e0.x, e0.y); dp[1] = pk2(e0.z, e0.w);
            dp[2] = pk2(e1.x, e1.y); dp[3] = pk2(e1.z, e1.w);
        }
        __syncthreads();
    }
}

// ---------------------------------------------------------------------------
// Phase 2: recurrence. grid = 16 (dir = bx>>3, batch group = bx&7), 512 thr.
// xg: per-thread 3x dwordx4 register prefetch (1 step ahead); barrier is
// lgkm-only so gathers span it. xr/xz become MFMA acc-inits.
// ---------------------------------------------------------------------------
__global__ __launch_bounds__(512, 2)
void gru_rnn_kernel(const int* __restrict__ inp,
                    const float* __restrict__ Whh_f, const float* __restrict__ bhh_f,
                    const float* __restrict__ Whh_b, const float* __restrict__ bhh_b,
                    const float* __restrict__ W_lin, const float* __restrict__ b_lin,
                    const unsigned short* __restrict__ G,
                    float* __restrict__ out) {
    __shared__ int            toks[16][513];          // 32.8 KB
    __shared__ unsigned short hB[2 * HBUF];           // 17.9 KB dbuf h (bf16)
    __shared__ float          bhnS[256];              // 1 KB
    __shared__ float          hs[16 * HS_STR];        // 16.6 KB epilogue

    const int tid  = threadIdx.x;
    const int lane = tid & 63;
    const int w    = tid >> 6;          // wave 0..7 (owns cols [32w,32w+32))
    const int b    = lane & 15;         // batch within group
    const int q    = lane >> 4;
    const int d    = blockIdx.x >> 3;   // 0 fwd, 1 bwd
    const int b0   = (blockIdx.x & 7) * 16;

    const float* Whh = d ? Whh_b : Whh_f;
    const float* bhh = d ? bhh_b : bhh_f;

    // W_hh as 48 A-fragments (pre-scaled): tile t = 2*gate + half.
    s16x8 wreg[48];
#pragma unroll
    for (int t = 0; t < 6; ++t) {
        const int orig = (t >> 1) * 256 + 32 * w + ((t & 1) << 4) + b;
        const float scl = (t < 4) ? SRF : SNF;
#pragma unroll
        for (int kt = 0; kt < 8; ++kt) {
            const float* p = Whh + orig * 256 + kt * 32 + q * 8;
            wreg[t * 8 + kt] =
                pack_bf8(*(const float4*)p, *(const float4*)(p + 4), scl);
        }
    }

    for (int i = tid; i < 16 * 512; i += 512) {
        int bb = i >> 9, t = i & 511;
        toks[bb][t] = inp[(b0 + bb) * 512 + t];
    }
    for (int i = tid; i < 2 * HBUF; i += 512) hB[i] = 0;   // h0 = 0
    if (tid < 256) bhnS[tid] = SNF * bhh[512 + tid];
    __syncthreads();

    const int hbq = b * HB_STR + q * 8;
    // this thread's 48 B gate-chunk base inside a token row
    const unsigned short* Gt = G + (size_t)(((d * 8 + w) * 4 + q) * 24);

    float hreg[8];
#pragma unroll
    for (int i = 0; i < 8; ++i) hreg[i] = 0.f;

    // prologue: prefetch xg for step 0
    uint4 p0, p1, pnx;
    {
        const int tt = d ? 511 : 0;
        const unsigned short* gb = Gt + (size_t)toks[b][tt] * GCOLS;
        p0  = *(const uint4*)(gb);
        p1  = *(const uint4*)(gb + 8);
        pnx = *(const uint4*)(gb + 16);
    }

#pragma unroll 2
    for (int ts = 0; ts < 512; ++ts) {
        const int rb = (ts & 1) * HBUF;
        const int wb = ((ts + 1) & 1) * HBUF;

        // 1) consume prefetched xg: fold xr/xz into acc-inits, keep xn packed
        f32x4 arI0 = {bf_lo(p0.x), bf_hi(p0.x), bf_lo(p0.y), bf_hi(p0.y)};
        f32x4 azI0 = {bf_lo(p0.z), bf_hi(p0.z), bf_lo(p0.w), bf_hi(p0.w)};
        f32x4 arI1 = {bf_lo(p1.x), bf_hi(p1.x), bf_lo(p1.y), bf_hi(p1.y)};
        f32x4 azI1 = {bf_lo(p1.z), bf_hi(p1.z), bf_lo(p1.w), bf_hi(p1.w)};
        const uint4 nn = pnx;

        // 2) issue NEXT step's gather (regs; flies across the lgkm barrier)
        {
            const int s1 = (ts < 511) ? ts + 1 : 511;
            const int tt = d ? 511 - s1 : s1;
            const unsigned short* gb = Gt + (size_t)toks[b][tt] * GCOLS;
            p0  = *(const uint4*)(gb);
            p1  = *(const uint4*)(gb + 8);
            pnx = *(const uint4*)(gb + 16);
        }

        // 3) two column-halves, gate-major schedule (R12)
#pragma unroll
        for (int l = 0; l < 2; ++l) {
            f32x4 ar = l ? arI1 : arI0;
            f32x4 az = l ? azI1 : azI0;
            __builtin_amdgcn_s_setprio(1);
            // pass A: r and z gates (16 MFMA, 2 independent chains)
#pragma unroll
            for (int kt = 0; kt < 8; ++kt) {
                s16x8 hf = *(const s16x8*)&hB[rb + hbq + kt * 32];
                ar = mfma16(wreg[(0 + l) * 8 + kt], hf, ar);
                az = mfma16(wreg[(2 + l) * 8 + kt], hf, az);
            }
            // pass B: n gate (8 MFMA) — rg/zg trans overlap its drain
            f32x4 an = *(const f32x4*)&bhnS[32 * w + 16 * l + 4 * q];
#pragma unroll
            for (int kt = 0; kt < 8; ++kt) {
                s16x8 hf = *(const s16x8*)&hB[rb + hbq + kt * 32];
                an = mfma16(wreg[(4 + l) * 8 + kt], hf, an);
            }
            __builtin_amdgcn_s_setprio(0);

            float rg[4], zg[4];
#pragma unroll
            for (int r = 0; r < 4; ++r) {
                rg[r] = sig2(ar[r]);
                zg[r] = sig2(az[r]);
            }
            const unsigned nx0 = l ? nn.z : nn.x;
            const unsigned nx1 = l ? nn.w : nn.y;
            const float xn[4] = {bf_lo(nx0), bf_hi(nx0), bf_lo(nx1), bf_hi(nx1)};
#pragma unroll
            for (int r = 0; r < 4; ++r) {
                float tg = sig2(fmaf(rg[r], an[r], xn[r]));
                float ng = fmaf(-2.0f, tg, 1.0f);
                const int i = l * 4 + r;
                hreg[i] = fmaf(zg[r], hreg[i] - ng, ng);
            }
            // write this half's h_new (bf16) to the other h buffer
            unsigned h0 = pk2(hreg[l * 4 + 0], hreg[l * 4 + 1]);
            unsigned h1 = pk2(hreg[l * 4 + 2], hreg[l * 4 + 3]);
            *(uint2*)&hB[wb + b * HB_STR + 32 * w + 16 * l + 4 * q] =
                make_uint2(h0, h1);
        }
        // 4) lgkm-only barrier: h writes visible; gathers keep flying
        lgkm_barrier();
    }

    // epilogue: out[b][c] += h_d[b] . W_lin[c, d*256:+256]  (+ b_lin once)
#pragma unroll
    for (int l = 0; l < 2; ++l) {
        f32x4 v = {hreg[l * 4 + 0], hreg[l * 4 + 1],
                   hreg[l * 4 + 2], hreg[l * 4 + 3]};
        *(f32x4*)&hs[b * HS_STR + 32 * w + 16 * l + 4 * q] = v;
    }
    __syncthreads();
    if (tid < 160) {
        int bb = tid / 10;
        int c  = tid - bb * 10;
        float acc = d ? 0.0f : b_lin[c];
        const float* wl = W_lin + c * 512 + d * 256;
        const float* hp = &hs[bb * HS_STR];
        for (int i = 0; i < 256; ++i) acc += hp[i] * wl[i];
        atomicAdd(&out[(b0 + bb) * 10 + c], acc);
    }
}

// ---------------------------------------------------------------------------
extern "C" void kernel_launch(void* const* d_in, const int* in_sizes, int n_in,
                              void* d_out, int out_size, void* d_ws, size_t ws_size,
                              hipStream_t stream) {
    const int*   inp   = (const int*)d_in[0];
    const float* emb   = (const float*)d_in[1];
    const float* Wih_f = (const float*)d_in[2];
    const float* Whh_f = (const float*)d_in[3];
    const float* bih_f = (const float*)d_in[4];
    const float* bhh_f = (const float*)d_in[5];
    const float* Wih_b = (const float*)d_in[6];
    const float* Whh_b = (const float*)d_in[7];
    const float* bih_b = (const float*)d_in[8];
    const float* bhh_b = (const float*)d_in[9];
    const float* W_lin = (const float*)d_in[10];
    const float* b_lin = (const float*)d_in[11];
    float* out = (float*)d_out;
    unsigned short* G = (unsigned short*)d_ws;   // 30000*1536*2 B = 92.16 MB

    hipMemsetAsync(d_out, 0, (size_t)out_size * sizeof(float), stream);
    hipLaunchKernelGGL(gru_table_kernel, dim3(2, 128), dim3(512), 0, stream,
                       emb, Wih_f, bih_f, bhh_f, Wih_b, bih_b, bhh_b, G);
    hipLaunchKernelGGL(gru_rnn_kernel, dim3(16), dim3(512), 0, stream,
                       inp, Whh_f, bhh_f, Whh_b, bhh_b, W_lin, b_lin, G, out);
}